// Round 1
// baseline (5222.589 us; speedup 1.0000x reference)
//
#include <hip/hip_runtime.h>
#include <math.h>

// Problem constants
#define BATCH 16
#define IN_F 64
#define OUT_F 64
#define HH 256
#define WW 256
#define KK 3
#define EPS 1e-5f
#define C_EQ (1.0f / 24.0f)   // 1/sqrt(64*3*3)

// Tiling
#define TH 16      // rows per tile
#define OCT 4      // output channels per block
#define XS_STRIDE 260  // padded row stride (multiple of 4 for b128 alignment)

__global__ __launch_bounds__(256, 2) void conv_mod_kernel(
    const float* __restrict__ x,
    const float* __restrict__ weight,
    float* __restrict__ out)
{
    // LDS: demodulated weights [ic][oc_local][kh] as float4 (x,y,z = kw0..2)
    __shared__ __align__(16) float4 ws[IN_F][OCT][KK];          // 64*4*3*16 = 12 KB
    __shared__ __align__(16) float xs[TH + 2][XS_STRIDE];       // 18*260*4 = 18.7 KB

    const int tid = threadIdx.x;
    const int tx = tid & 15;       // 0..15 : column group (16 px each)
    const int ty = tid >> 4;       // 0..15 : row within tile
    const int ocg    = blockIdx.x; // 0..15 : output-channel group (fastest for L2 reuse of x)
    const int tile_y = blockIdx.y; // 0..15
    const int b      = blockIdx.z; // 0..15

    // ---- Weight prep: demodulate OCT channels for this block ----
    {
        const int o_l = tid >> 6;          // 0..3 (one wave per output channel)
        const int i   = tid & 63;          // input channel = lane
        const int o   = ocg * OCT + o_l;
        const float* wp = weight + ((size_t)o * IN_F + i) * 9;
        float w0 = wp[0], w1 = wp[1], w2 = wp[2];
        float w3 = wp[3], w4 = wp[4], w5 = wp[5];
        float w6 = wp[6], w7 = wp[7], w8 = wp[8];
        float s = w0*w0 + w1*w1 + w2*w2 + w3*w3 + w4*w4 + w5*w5 + w6*w6 + w7*w7 + w8*w8;
        s *= (C_EQ * C_EQ);
        // 64-lane butterfly reduce (wave-aligned: lanes = tid%64, o_l uniform in wave)
        #pragma unroll
        for (int off = 1; off < 64; off <<= 1)
            s += __shfl_xor(s, off, 64);
        const float sc = C_EQ * rsqrtf(s + EPS);
        ws[i][o_l][0] = make_float4(w0 * sc, w1 * sc, w2 * sc, 0.0f);
        ws[i][o_l][1] = make_float4(w3 * sc, w4 * sc, w5 * sc, 0.0f);
        ws[i][o_l][2] = make_float4(w6 * sc, w7 * sc, w8 * sc, 0.0f);
    }

    float acc[OCT][16];
    #pragma unroll
    for (int o = 0; o < OCT; ++o)
        #pragma unroll
        for (int p = 0; p < 16; ++p)
            acc[o][p] = 0.0f;

    const int gh0 = tile_y * TH;       // first output row of tile
    const int gh  = gh0 + ty;          // this thread's output row
    const int c0  = tx * 16;           // this thread's first output col

    for (int ic = 0; ic < IN_F; ++ic) {
        __syncthreads();   // protect xs from previous iteration's readers
        // ---- stage x tile: rows gh0-1 .. gh0+16, cols -1 .. 256 (zero halo) ----
        const float* xplane = x + ((size_t)(b * IN_F + ic) * HH) * WW;
        for (int idx = tid; idx < (TH + 2) * 258; idx += 256) {
            const int r = idx / 258;
            const int c = idx - r * 258;
            const int rg = gh0 - 1 + r;
            const int cg = c - 1;
            float v = 0.0f;
            if ((unsigned)rg < (unsigned)HH && (unsigned)cg < (unsigned)WW)
                v = xplane[rg * WW + cg];
            xs[r][c] = v;
        }
        __syncthreads();

        // ---- compute: 3 kh rows, 4 oc, 16 px, 3 kw = 576 FMA ----
        #pragma unroll
        for (int kh = 0; kh < KK; ++kh) {
            float xr[18];
            const float* row = &xs[ty + kh][c0];   // 16B-aligned base
            #pragma unroll
            for (int j = 0; j < 18; ++j)
                xr[j] = row[j];
            #pragma unroll
            for (int o = 0; o < OCT; ++o) {
                const float4 wv = ws[ic][o][kh];   // broadcast read
                #pragma unroll
                for (int p = 0; p < 16; ++p)
                    acc[o][p] += xr[p] * wv.x + xr[p + 1] * wv.y + xr[p + 2] * wv.z;
            }
        }
    }

    // ---- write out: 4 float4 stores per oc, coalesced ----
    #pragma unroll
    for (int o = 0; o < OCT; ++o) {
        float* orow = out + (((size_t)(b * OUT_F + ocg * OCT + o) * HH + gh) * WW) + c0;
        #pragma unroll
        for (int q = 0; q < 4; ++q) {
            float4 v = make_float4(acc[o][4*q], acc[o][4*q+1], acc[o][4*q+2], acc[o][4*q+3]);
            reinterpret_cast<float4*>(orow)[q] = v;
        }
    }
}

extern "C" void kernel_launch(void* const* d_in, const int* in_sizes, int n_in,
                              void* d_out, int out_size, void* d_ws, size_t ws_size,
                              hipStream_t stream) {
    const float* x = (const float*)d_in[0];
    const float* w = (const float*)d_in[1];
    float* out = (float*)d_out;
    dim3 grid(OUT_F / OCT, HH / TH, BATCH);   // (16 ocg, 16 tiles, 16 batch)
    conv_mod_kernel<<<grid, 256, 0, stream>>>(x, w, out);
}

// Round 2
// 1249.266 us; speedup vs baseline: 4.1805x; 4.1805x over previous
//
#include <hip/hip_runtime.h>
#include <math.h>

// Problem constants
#define BATCH 16
#define IN_F 64
#define OUT_F 64
#define HH 256
#define WW 256
#define EPS 1e-5f
#define C_EQ (1.0f / 24.0f)   // 1/sqrt(64*3*3)

// Tiling: block = 256 threads = 4 waves.
// lane l (0..63) -> cols [4l, 4l+4);  wave w (0..3) -> out rows [4w, 4w+4).
// Tile = 16 rows x 256 cols x OCT output channels.
#define OCT 4
#define TH 16
#define XROWS 18            // 16 + 2 halo rows
#define XSTR 264            // padded row stride (floats), 16B-aligned rows
// col c of the image maps to LDS index c+4 (idx 3 = col -1 halo, idx 260 = col 256 halo)

__global__ __launch_bounds__(256, 2) void conv_mod_kernel(
    const float* __restrict__ x,
    const float* __restrict__ weight,
    float* __restrict__ out)
{
    __shared__ __align__(16) float4 ws[IN_F][OCT][3];     // 12 KB demodulated weights
    __shared__ __align__(16) float xs[2][XROWS][XSTR];    // 2 x 19 KB double-buffered x tile

    const int tid    = threadIdx.x;
    const int lane   = tid & 63;
    const int wv     = tid >> 6;
    const int ocg    = blockIdx.x;   // fastest -> 16 blocks sharing x tile dispatch together
    const int tile_y = blockIdx.y;
    const int b      = blockIdx.z;
    const int gh0    = tile_y * TH;
    const int c0     = lane * 4;     // first col this thread owns
    const int r0     = wv * 4;       // first out row (tile-relative) this thread owns

    // ---- weight prep: one wave per output channel, lane = input channel ----
    {
        const int o = ocg * OCT + wv;
        const float* wp = weight + ((size_t)o * IN_F + lane) * 9;
        float w0=wp[0],w1=wp[1],w2=wp[2],w3=wp[3],w4=wp[4],w5=wp[5],w6=wp[6],w7=wp[7],w8=wp[8];
        float s = w0*w0+w1*w1+w2*w2+w3*w3+w4*w4+w5*w5+w6*w6+w7*w7+w8*w8;
        s *= C_EQ * C_EQ;
        #pragma unroll
        for (int off = 1; off < 64; off <<= 1) s += __shfl_xor(s, off, 64);
        const float sc = C_EQ * rsqrtf(s + EPS);
        ws[lane][wv][0] = make_float4(w0*sc, w1*sc, w2*sc, 0.f);
        ws[lane][wv][1] = make_float4(w3*sc, w4*sc, w5*sc, 0.f);
        ws[lane][wv][2] = make_float4(w6*sc, w7*sc, w8*sc, 0.f);
    }

    // ---- one-time zero fill: halo cols (never overwritten by staging) + edge rows ----
    for (int i2 = tid; i2 < 2 * XROWS; i2 += 256) {
        const int bufz = i2 / XROWS, r = i2 - bufz * XROWS;
        xs[bufz][r][3]   = 0.f;   // col -1
        xs[bufz][r][260] = 0.f;   // col 256
    }
    if (tile_y == 0)
        for (int c = tid; c < XSTR; c += 256) { xs[0][0][c] = 0.f;  xs[1][0][c] = 0.f; }
    if (tile_y == (HH / TH) - 1)
        for (int c = tid; c < XSTR; c += 256) { xs[0][17][c] = 0.f; xs[1][17][c] = 0.f; }

    const float* xb = x + (size_t)b * IN_F * HH * WW;

    // ---- prologue: stage ic=0 into buf 0 via global_load_lds (wave w -> rows w, w+4, ...) ----
    for (int r = wv; r < XROWS; r += 4) {
        const int gr = gh0 - 1 + r;
        if ((unsigned)gr < (unsigned)HH) {
            const float* src = xb + (size_t)gr * WW + c0;   // per-lane 16B chunk
            __builtin_amdgcn_global_load_lds(
                (const __attribute__((address_space(1))) void*)src,
                (__attribute__((address_space(3))) void*)&xs[0][r][4], 16, 0, 0);
        }
    }
    __syncthreads();

    float acc[OCT][4][4];
    #pragma unroll
    for (int o = 0; o < OCT; ++o)
        #pragma unroll
        for (int rr = 0; rr < 4; ++rr)
            #pragma unroll
            for (int p = 0; p < 4; ++p) acc[o][rr][p] = 0.f;

    for (int ic = 0; ic < IN_F; ++ic) {
        const int buf = ic & 1;
        // prefetch next ic into the other buffer; latency hides under the 576 FMAs
        if (ic + 1 < IN_F) {
            const float* plane = xb + (size_t)(ic + 1) * HH * WW;
            for (int r = wv; r < XROWS; r += 4) {
                const int gr = gh0 - 1 + r;
                if ((unsigned)gr < (unsigned)HH) {
                    const float* src = plane + (size_t)gr * WW + c0;
                    __builtin_amdgcn_global_load_lds(
                        (const __attribute__((address_space(1))) void*)src,
                        (__attribute__((address_space(3))) void*)&xs[buf ^ 1][r][4], 16, 0, 0);
                }
            }
        }
        // ---- compute: 6 input rows, each read as 3 conflict-free ds_read_b128 ----
        #pragma unroll
        for (int j = 0; j < 6; ++j) {
            const float4 L  = *(const float4*)&xs[buf][r0 + j][c0];       // cols c0-4..c0-1 (use .w)
            const float4 M  = *(const float4*)&xs[buf][r0 + j][c0 + 4];   // cols c0..c0+3
            const float4 Rt = *(const float4*)&xs[buf][r0 + j][c0 + 8];   // cols c0+4..c0+7 (use .x)
            const float xv0 = L.w, xv1 = M.x, xv2 = M.y, xv3 = M.z, xv4 = M.w, xv5 = Rt.x;
            #pragma unroll
            for (int kh = 0; kh < 3; ++kh) {
                const int R = j - kh;               // out row (thread-relative) this (j,kh) feeds
                if (R < 0 || R > 3) continue;       // resolved at compile time
                #pragma unroll
                for (int o = 0; o < OCT; ++o) {
                    const float4 w4 = ws[ic][o][kh];   // broadcast read, conflict-free
                    acc[o][R][0] += xv0*w4.x + xv1*w4.y + xv2*w4.z;
                    acc[o][R][1] += xv1*w4.x + xv2*w4.y + xv3*w4.z;
                    acc[o][R][2] += xv2*w4.x + xv3*w4.y + xv4*w4.z;
                    acc[o][R][3] += xv3*w4.x + xv4*w4.y + xv5*w4.z;
                }
            }
        }
        __syncthreads();   // drains prefetch vmcnt + protects buffer swap
    }

    // ---- epilogue: coalesced float4 stores ----
    #pragma unroll
    for (int o = 0; o < OCT; ++o) {
        const int oc = ocg * OCT + o;
        #pragma unroll
        for (int R = 0; R < 4; ++R) {
            float* orow = out + (((size_t)(b * OUT_F + oc) * HH + (gh0 + r0 + R)) * WW) + c0;
            *reinterpret_cast<float4*>(orow) =
                make_float4(acc[o][R][0], acc[o][R][1], acc[o][R][2], acc[o][R][3]);
        }
    }
}

extern "C" void kernel_launch(void* const* d_in, const int* in_sizes, int n_in,
                              void* d_out, int out_size, void* d_ws, size_t ws_size,
                              hipStream_t stream) {
    const float* x = (const float*)d_in[0];
    const float* w = (const float*)d_in[1];
    float* out = (float*)d_out;
    dim3 grid(OUT_F / OCT, HH / TH, BATCH);   // (16 ocg, 16 tiles, 16 batch) — ocg fastest
    conv_mod_kernel<<<grid, 256, 0, stream>>>(x, w, out);
}

// Round 3
// 722.867 us; speedup vs baseline: 7.2248x; 1.7282x over previous
//
#include <hip/hip_runtime.h>
#include <hip/hip_bf16.h>
#include <math.h>

#define BATCH 16
#define ICH 64
#define OCH 64
#define HH 256
#define WW 256
#define HW 65536
#define EPS 1e-5f
#define C_EQ (1.0f / 24.0f)

typedef __attribute__((ext_vector_type(8))) short short8;   // bf16x8 MFMA operand
typedef __attribute__((ext_vector_type(4))) float floatx4;  // fp32x4 accumulator

// Pixel tile: TR x TC, halo (TR+2) x (TC+2)
#define TR 4
#define TC 64
#define XROWS 6
#define XCOLS 66
#define XPIXB 64                 // bytes per pixel in LDS (32 ic * bf16), 4 slots of 16B
#define XROWB (XCOLS * XPIXB)    // 4224
#define XHALFB (XROWS * XROWB)   // 25344
#define LDS_BYTES (2 * XHALFB)   // 50688 (weight frag area 36864 B reuses this before staging)

static __device__ __forceinline__ unsigned short f2bf(float v) {
    __hip_bfloat16 b = __float2bfloat16(v);
    return *reinterpret_cast<unsigned short*>(&b);
}

__global__ __launch_bounds__(256, 2) void conv_mfma_kernel(
    const float* __restrict__ x,
    const float* __restrict__ wgt,
    float* __restrict__ out)
{
    __shared__ __align__(16) char lds[LDS_BYTES];

    const int tid  = threadIdx.x;
    const int lane = tid & 63;
    const int wv   = tid >> 6;
    const int n_l  = lane & 15;   // MFMA col (pixel within frag)
    const int G_l  = lane >> 4;   // MFMA k-group

    // ================= weight demod -> per-wave A-frag registers =================
    // thread t: oc = t>>2, ic-range [ (t&3)*16, +16 ), all 9 taps = 144 contiguous floats
    const int oc_t = tid >> 2;
    const int icr  = tid & 3;
    float wf[144];
    {
        const float* wb = wgt + (size_t)tid * 144;
        #pragma unroll
        for (int i = 0; i < 36; ++i) {
            const float4 v = reinterpret_cast<const float4*>(wb)[i];
            wf[4*i+0] = v.x; wf[4*i+1] = v.y; wf[4*i+2] = v.z; wf[4*i+3] = v.w;
        }
    }
    float s = 0.f;
    #pragma unroll
    for (int i = 0; i < 144; ++i) s += wf[i] * wf[i];
    s += __shfl_xor(s, 1, 64);
    s += __shfl_xor(s, 2, 64);
    const float sc = C_EQ * rsqrtf(s * (C_EQ * C_EQ) + EPS);

    short8 afrag[18];   // 18 K-chunks (half*9 + tap), 4 VGPR each
    {
        const int oc_l = (wv << 4) + n_l;
        #pragma unroll
        for (int h = 0; h < 2; ++h) {
            __syncthreads();
            if ((icr >> 1) == h) {
                // this thread's ic-range lies in half h: write frag-layout bf16
                #pragma unroll
                for (int tap = 0; tap < 9; ++tap) {
                    #pragma unroll
                    for (int ss = 0; ss < 2; ++ss) {
                        const int G = ((icr & 1) << 1) + ss;
                        unsigned int pk[4];
                        #pragma unroll
                        for (int jp = 0; jp < 4; ++jp) {
                            const unsigned short lo = f2bf(wf[(ss*8 + 2*jp + 0)*9 + tap] * sc);
                            const unsigned short hi = f2bf(wf[(ss*8 + 2*jp + 1)*9 + tap] * sc);
                            pk[jp] = (unsigned int)lo | ((unsigned int)hi << 16);
                        }
                        uint4 w4 = make_uint4(pk[0], pk[1], pk[2], pk[3]);
                        *reinterpret_cast<uint4*>(&lds[(((tap*64 + oc_t)*4 + G) << 4)]) = w4;
                    }
                }
            }
            __syncthreads();
            #pragma unroll
            for (int t9 = 0; t9 < 9; ++t9)
                afrag[h*9 + t9] = *reinterpret_cast<const short8*>(
                    &lds[(((t9*64 + oc_l)*4 + G_l) << 4)]);
        }
    }
    __syncthreads();   // weight area now dead; safe to overwrite with x

    // ================= stage x tile (both ic-halves), channel-last bf16 =================
    const int gr0 = blockIdx.y * TR;
    const int gc0 = blockIdx.x * TC;
    const int b   = blockIdx.z;
    const float* xb = x + (size_t)b * ICH * HW;

    for (int p = wv; p < 48; p += 4) {
        const int h  = p / 24;
        const int pr = (p % 24) >> 2;   // 0..5
        const int G  = p & 3;
        const int gr = gr0 - 1 + pr;
        const int icb = h*32 + G*8;
        const bool rok = ((unsigned)gr < (unsigned)HH);
        // main pass: lane -> pc = lane+1, gc = gc0 + lane (always col-in-bounds)
        {
            const float* src = xb + (size_t)icb * HW + (size_t)gr * WW + gc0 + lane;
            float v[8];
            #pragma unroll
            for (int q = 0; q < 8; ++q) v[q] = rok ? src[(size_t)q * HW] : 0.f;
            const int pc = lane + 1;
            const int addr = h*XHALFB + pr*XROWB + pc*XPIXB + ((G ^ ((pc >> 1) & 3)) << 4);
            uint4 w4;
            w4.x = (unsigned)f2bf(v[0]) | ((unsigned)f2bf(v[1]) << 16);
            w4.y = (unsigned)f2bf(v[2]) | ((unsigned)f2bf(v[3]) << 16);
            w4.z = (unsigned)f2bf(v[4]) | ((unsigned)f2bf(v[5]) << 16);
            w4.w = (unsigned)f2bf(v[6]) | ((unsigned)f2bf(v[7]) << 16);
            *reinterpret_cast<uint4*>(&lds[addr]) = w4;
        }
        // edge cols: lanes 0,1 handle pc = 0 and 65
        if (lane < 2) {
            const int pc = lane * 65;
            const int gc = gc0 - 1 + pc;
            const bool ok = rok && ((unsigned)gc < (unsigned)WW);
            const float* src = xb + (size_t)icb * HW + (size_t)gr * WW + gc;
            float v[8];
            #pragma unroll
            for (int q = 0; q < 8; ++q) v[q] = ok ? src[(size_t)q * HW] : 0.f;
            const int addr = h*XHALFB + pr*XROWB + pc*XPIXB + ((G ^ ((pc >> 1) & 3)) << 4);
            uint4 w4;
            w4.x = (unsigned)f2bf(v[0]) | ((unsigned)f2bf(v[1]) << 16);
            w4.y = (unsigned)f2bf(v[2]) | ((unsigned)f2bf(v[3]) << 16);
            w4.z = (unsigned)f2bf(v[4]) | ((unsigned)f2bf(v[5]) << 16);
            w4.w = (unsigned)f2bf(v[6]) | ((unsigned)f2bf(v[7]) << 16);
            *reinterpret_cast<uint4*>(&lds[addr]) = w4;
        }
    }
    __syncthreads();

    // ================= main loop: 18 chunks x 16 frags, zero VALU addr math =================
    int colp[4][3];   // per-lane col-part of ds addr, [c_base/16][kw]
    #pragma unroll
    for (int cb = 0; cb < 4; ++cb)
        #pragma unroll
        for (int kw = 0; kw < 3; ++kw) {
            const int pcv = cb*16 + n_l + kw;
            colp[cb][kw] = pcv * XPIXB + ((G_l ^ ((pcv >> 1) & 3)) << 4);
        }

    floatx4 acc[16];
    #pragma unroll
    for (int f = 0; f < 16; ++f) acc[f] = (floatx4){0.f, 0.f, 0.f, 0.f};

    #pragma unroll
    for (int kc = 0; kc < 18; ++kc) {
        const int h = kc / 9, tap = kc % 9;
        const int kh = tap / 3, kw = tap % 3;
        #pragma unroll
        for (int f = 0; f < 16; ++f) {
            const int fr = f >> 2, cb = f & 3;
            const short8 bfrag = *reinterpret_cast<const short8*>(
                &lds[h*XHALFB + (fr + kh)*XROWB + colp[cb][kw]]);
            acc[f] = __builtin_amdgcn_mfma_f32_16x16x32_bf16(afrag[kc], bfrag, acc[f], 0, 0, 0);
        }
    }

    // ================= epilogue: fp32 stores =================
    // lane holds D[row = G_l*4 + ri (oc within wave)][col = n_l (pixel within frag)]
    float* ob = out + ((size_t)(b*OCH + (wv << 4) + (G_l << 2)) * HW)
                    + (size_t)gr0 * WW + gc0 + n_l;
    #pragma unroll
    for (int f = 0; f < 16; ++f) {
        const int fr = f >> 2, cb = f & 3;
        #pragma unroll
        for (int ri = 0; ri < 4; ++ri)
            ob[(size_t)ri * HW + fr * WW + cb * 16] = acc[f][ri];
    }
}

extern "C" void kernel_launch(void* const* d_in, const int* in_sizes, int n_in,
                              void* d_out, int out_size, void* d_ws, size_t ws_size,
                              hipStream_t stream) {
    const float* x = (const float*)d_in[0];
    const float* w = (const float*)d_in[1];
    float* out = (float*)d_out;
    dim3 grid(WW / TC, HH / TR, BATCH);   // (4, 64, 16)
    conv_mfma_kernel<<<grid, 256, 0, stream>>>(x, w, out);
}

// Round 4
// 699.467 us; speedup vs baseline: 7.4665x; 1.0335x over previous
//
#include <hip/hip_runtime.h>
#include <hip/hip_bf16.h>
#include <math.h>

#define BATCH 16
#define ICH 64
#define OCH 64
#define HH 256
#define WW 256
#define HW 65536
#define EPS 1e-5f
#define C_EQ (1.0f / 24.0f)

typedef __attribute__((ext_vector_type(8))) short short8;   // bf16x8 MFMA operand
typedef __attribute__((ext_vector_type(4))) float floatx4;  // fp32x4 accumulator

// Pixel tile: TR x TC, halo (TR+2) x (TC+2)
#define TR 4
#define TC 64
#define XROWS 6
#define XCOLS 66
#define XPIXB 64                 // bytes per pixel in LDS (32 ic * bf16), 4 slots of 16B
#define XROWB (XCOLS * XPIXB)    // 4224
#define XHALFB (XROWS * XROWB)   // 25344
#define LDS_BYTES (2 * XHALFB)   // 50688
#define WS_BYTES (18 * 64 * 4 * 16)   // 73728 B of bf16 A-frags in d_ws

static __device__ __forceinline__ unsigned short f2bf(float v) {
    __hip_bfloat16 b = __float2bfloat16(v);
    return *reinterpret_cast<unsigned short*>(&b);
}

// ============ kernel 1: demodulate weights -> bf16 A-frag layout in d_ws ============
// grid(4) x block(64). thread = (oc = bx*16 + tid>>2, q = tid&3 -> ic [16q,16q+16)).
// Frag layout: 16B chunk at ((kc*64 + oc)*4 + G)*16, kc = h*9+tap, chunk dword jp =
// bf16(w[oc][32h+8G+2jp]) | bf16(w[oc][32h+8G+2jp+1])<<16, all scaled by sc.
__global__ void weight_prep_kernel(const float* __restrict__ wgt,
                                   unsigned int* __restrict__ wsout)
{
    const int tid = threadIdx.x;
    const int oc  = blockIdx.x * 16 + (tid >> 2);
    const int q   = tid & 3;
    const float* wb = wgt + ((size_t)oc * 64 + q * 16) * 9;   // this thread's 144 floats

    float s = 0.f;
    #pragma unroll 4
    for (int i = 0; i < 36; ++i) {
        const float4 v = reinterpret_cast<const float4*>(wb)[i];
        s += v.x*v.x + v.y*v.y + v.z*v.z + v.w*v.w;
    }
    s += __shfl_xor(s, 1, 64);
    s += __shfl_xor(s, 2, 64);                      // sum over the 4-thread (oc) group
    const float sc = C_EQ * rsqrtf(s * (C_EQ * C_EQ) + EPS);

    const int h = q >> 1;
    #pragma unroll
    for (int s2 = 0; s2 < 2; ++s2) {
        const int G = (q & 1) * 2 + s2;
        #pragma unroll
        for (int jp = 0; jp < 4; ++jp) {
            const float* r0 = wb + (8 * s2 + 2 * jp) * 9;   // ic row 2jp   (L2-hot)
            const float* r1 = r0 + 9;                       // ic row 2jp+1
            #pragma unroll
            for (int t = 0; t < 9; ++t) {
                const unsigned int d = (unsigned)f2bf(r0[t] * sc)
                                     | ((unsigned)f2bf(r1[t] * sc) << 16);
                wsout[(((h * 9 + t) * 64 + oc) * 4 + G) * 4 + jp] = d;
            }
        }
    }
}

// ============ kernel 2: implicit-GEMM conv, A-frags straight from d_ws ============
__global__ __launch_bounds__(256, 2) void conv_mfma_kernel(
    const float* __restrict__ x,
    const unsigned int* __restrict__ wfrag,
    float* __restrict__ out)
{
    __shared__ __align__(16) char lds[LDS_BYTES];

    const int tid  = threadIdx.x;
    const int lane = tid & 63;
    const int wv   = tid >> 6;
    const int n_l  = lane & 15;   // MFMA col (pixel within frag)
    const int G_l  = lane >> 4;   // MFMA k-group

    // ---- A-frags: 18 coalesced 16B loads from d_ws (L2-resident, no demod work) ----
    short8 afrag[18];
    {
        const int oc_l = (wv << 4) + n_l;
        const char* wsb = (const char*)wfrag;
        #pragma unroll
        for (int kc = 0; kc < 18; ++kc)
            afrag[kc] = *reinterpret_cast<const short8*>(
                wsb + (((kc * 64 + oc_l) * 4 + G_l) << 4));
    }

    // ---- stage x tile (both ic-halves), channel-last bf16 ----
    const int gr0 = blockIdx.y * TR;
    const int gc0 = blockIdx.x * TC;
    const int b   = blockIdx.z;
    const float* xb = x + (size_t)b * ICH * HW;

    for (int p = wv; p < 48; p += 4) {
        const int h  = p / 24;
        const int pr = (p % 24) >> 2;   // 0..5
        const int G  = p & 3;
        const int gr = gr0 - 1 + pr;
        const int icb = h * 32 + G * 8;
        const bool rok = ((unsigned)gr < (unsigned)HH);
        {
            const float* src = xb + (size_t)icb * HW + (size_t)gr * WW + gc0 + lane;
            float v[8];
            #pragma unroll
            for (int qq = 0; qq < 8; ++qq) v[qq] = rok ? src[(size_t)qq * HW] : 0.f;
            const int pc = lane + 1;
            const int addr = h*XHALFB + pr*XROWB + pc*XPIXB + ((G ^ ((pc >> 1) & 3)) << 4);
            uint4 w4;
            w4.x = (unsigned)f2bf(v[0]) | ((unsigned)f2bf(v[1]) << 16);
            w4.y = (unsigned)f2bf(v[2]) | ((unsigned)f2bf(v[3]) << 16);
            w4.z = (unsigned)f2bf(v[4]) | ((unsigned)f2bf(v[5]) << 16);
            w4.w = (unsigned)f2bf(v[6]) | ((unsigned)f2bf(v[7]) << 16);
            *reinterpret_cast<uint4*>(&lds[addr]) = w4;
        }
        if (lane < 2) {   // edge cols pc = 0 and 65
            const int pc = lane * 65;
            const int gc = gc0 - 1 + pc;
            const bool ok = rok && ((unsigned)gc < (unsigned)WW);
            const float* src = xb + (size_t)icb * HW + (size_t)gr * WW + gc;
            float v[8];
            #pragma unroll
            for (int qq = 0; qq < 8; ++qq) v[qq] = ok ? src[(size_t)qq * HW] : 0.f;
            const int addr = h*XHALFB + pr*XROWB + pc*XPIXB + ((G ^ ((pc >> 1) & 3)) << 4);
            uint4 w4;
            w4.x = (unsigned)f2bf(v[0]) | ((unsigned)f2bf(v[1]) << 16);
            w4.y = (unsigned)f2bf(v[2]) | ((unsigned)f2bf(v[3]) << 16);
            w4.z = (unsigned)f2bf(v[4]) | ((unsigned)f2bf(v[5]) << 16);
            w4.w = (unsigned)f2bf(v[6]) | ((unsigned)f2bf(v[7]) << 16);
            *reinterpret_cast<uint4*>(&lds[addr]) = w4;
        }
    }
    __syncthreads();

    // ---- main loop: 18 K-chunks x 16 frags, compile-time LDS offsets ----
    int colp[4][3];
    #pragma unroll
    for (int cb = 0; cb < 4; ++cb)
        #pragma unroll
        for (int kw = 0; kw < 3; ++kw) {
            const int pcv = cb * 16 + n_l + kw;
            colp[cb][kw] = pcv * XPIXB + ((G_l ^ ((pcv >> 1) & 3)) << 4);
        }

    floatx4 acc[16];
    #pragma unroll
    for (int f = 0; f < 16; ++f) acc[f] = (floatx4){0.f, 0.f, 0.f, 0.f};

    #pragma unroll
    for (int kc = 0; kc < 18; ++kc) {
        const int h = kc / 9, tap = kc % 9;
        const int kh = tap / 3, kw = tap % 3;
        #pragma unroll
        for (int f = 0; f < 16; ++f) {
            const int fr = f >> 2, cb = f & 3;
            const short8 bfrag = *reinterpret_cast<const short8*>(
                &lds[h*XHALFB + (fr + kh)*XROWB + colp[cb][kw]]);
            acc[f] = __builtin_amdgcn_mfma_f32_16x16x32_bf16(afrag[kc], bfrag, acc[f], 0, 0, 0);
        }
    }

    // ---- epilogue ----
    float* ob = out + ((size_t)(b*OCH + (wv << 4) + (G_l << 2)) * HW)
                    + (size_t)gr0 * WW + gc0 + n_l;
    #pragma unroll
    for (int f = 0; f < 16; ++f) {
        const int fr = f >> 2, cb = f & 3;
        #pragma unroll
        for (int ri = 0; ri < 4; ++ri)
            ob[(size_t)ri * HW + fr * WW + cb * 16] = acc[f][ri];
    }
}

extern "C" void kernel_launch(void* const* d_in, const int* in_sizes, int n_in,
                              void* d_out, int out_size, void* d_ws, size_t ws_size,
                              hipStream_t stream) {
    const float* x = (const float*)d_in[0];
    const float* w = (const float*)d_in[1];
    float* out = (float*)d_out;
    unsigned int* wsf = (unsigned int*)d_ws;   // needs WS_BYTES = 73728 <= ws_size

    weight_prep_kernel<<<dim3(4), 64, 0, stream>>>(w, wsf);
    dim3 grid(WW / TC, HH / TR, BATCH);   // (4, 64, 16)
    conv_mfma_kernel<<<grid, 256, 0, stream>>>(x, wsf, out);
}

// Round 5
// 308.244 us; speedup vs baseline: 16.9430x; 2.2692x over previous
//
#include <hip/hip_runtime.h>
#include <hip/hip_bf16.h>
#include <math.h>

#define BATCH 16
#define ICH 64
#define OCH 64
#define HH 256
#define WW 256
#define HW 65536
#define EPS 1e-5f
#define C_EQ (1.0f / 24.0f)

typedef __attribute__((ext_vector_type(8))) short short8;   // bf16x8 MFMA operand
typedef __attribute__((ext_vector_type(4))) float floatx4;  // fp32x4 accumulator

// d_ws layout: [0, 73728) bf16 A-frags ; [73728, +134217728) xT = x as [b][h][w][ic] bf16
#define AFRAG_BYTES (18 * 64 * 4 * 16)          // 73728
#define XT_BYTES ((size_t)BATCH * HH * WW * ICH * 2)   // 134217728
#define WS_NEEDED (AFRAG_BYTES + XT_BYTES)

static __device__ __forceinline__ unsigned short f2bf(float v) {
    __hip_bfloat16 b = __float2bfloat16(v);
    return *reinterpret_cast<unsigned short*>(&b);
}
static __device__ __forceinline__ unsigned int pk2(float a, float b) {
    return (unsigned int)f2bf(a) | ((unsigned int)f2bf(b) << 16);
}

// ============ kernel 1: demodulate weights -> bf16 A-frag layout (validated R4) ============
__global__ void weight_prep_kernel(const float* __restrict__ wgt,
                                   unsigned int* __restrict__ wsout)
{
    const int tid = threadIdx.x;
    const int oc  = blockIdx.x * 16 + (tid >> 2);
    const int q   = tid & 3;
    const float* wb = wgt + ((size_t)oc * 64 + q * 16) * 9;

    float s = 0.f;
    #pragma unroll 4
    for (int i = 0; i < 36; ++i) {
        const float4 v = reinterpret_cast<const float4*>(wb)[i];
        s += v.x*v.x + v.y*v.y + v.z*v.z + v.w*v.w;
    }
    s += __shfl_xor(s, 1, 64);
    s += __shfl_xor(s, 2, 64);
    const float sc = C_EQ * rsqrtf(s * (C_EQ * C_EQ) + EPS);

    const int h = q >> 1;
    #pragma unroll
    for (int s2 = 0; s2 < 2; ++s2) {
        const int G = (q & 1) * 2 + s2;
        #pragma unroll
        for (int jp = 0; jp < 4; ++jp) {
            const float* r0 = wb + (8 * s2 + 2 * jp) * 9;
            const float* r1 = r0 + 9;
            #pragma unroll
            for (int t = 0; t < 9; ++t) {
                const unsigned int d = (unsigned)f2bf(r0[t] * sc)
                                     | ((unsigned)f2bf(r1[t] * sc) << 16);
                wsout[(((h * 9 + t) * 64 + oc) * 4 + G) * 4 + jp] = d;
            }
        }
    }
}

// ============ kernel 2: NCHW fp32 -> [b][h][w][ic] bf16 (streaming transpose) ============
// block = (cb, h, b), 256 threads. Reads 64ic x 64col tile coalesced; writes 16B/lane coalesced.
__global__ __launch_bounds__(256, 8) void transpose_kernel(
    const float* __restrict__ x, unsigned int* __restrict__ xT)
{
    __shared__ float lds[64 * 65];   // [col][ic], stride 65 -> conflict-free both phases
    const int tid  = threadIdx.x;
    const int lane = tid & 63;
    const int wv   = tid >> 6;
    const int cb = blockIdx.x, h = blockIdx.y, b = blockIdx.z;

    const float* xrow = x + (size_t)b * ICH * HW + (size_t)h * WW + cb * 64;
    float v[16];
    #pragma unroll
    for (int i = 0; i < 16; ++i)
        v[i] = xrow[(size_t)(i * 4 + wv) * HW + lane];   // 256B coalesced per instr
    #pragma unroll
    for (int i = 0; i < 16; ++i)
        lds[lane * 65 + i * 4 + wv] = v[i];
    __syncthreads();

    const int col = tid >> 2;        // 0..63
    const int g   = tid & 3;         // 0..3
    const float* lp = &lds[col * 65];
    char* dst = (char*)xT + ((((size_t)b * HH + h) * WW + cb * 64 + col) << 7);  // pixel*128B
    #pragma unroll
    for (int r = 0; r < 2; ++r) {    // ic-half
        const int ich = r * 32 + g * 8;
        uint4 dw;
        dw.x = pk2(lp[ich + 0], lp[ich + 1]);
        dw.y = pk2(lp[ich + 2], lp[ich + 3]);
        dw.z = pk2(lp[ich + 4], lp[ich + 5]);
        dw.w = pk2(lp[ich + 6], lp[ich + 7]);
        *reinterpret_cast<uint4*>(dst + r * 64 + g * 16) = dw;   // 16B/lane coalesced
    }
}

// ============ kernel 3: LDS-free implicit-GEMM conv (B-frags straight from xT) ============
// block: 64 oc x 4 rows x 64 cols. wave wv owns col-slice [wv*16, +16); all 64 oc.
__global__ __launch_bounds__(256, 3) void conv_mfma_global(
    const char* __restrict__ ws,          // A-frags at offset 0, xT at AFRAG_BYTES
    float* __restrict__ out)
{
    const int tid  = threadIdx.x;
    const int lane = tid & 63;
    const int wv   = tid >> 6;     // col-slice
    const int n_l  = lane & 15;    // MFMA col (pixel) / A-row (oc within 16)
    const int G_l  = lane >> 4;    // MFMA k-group (8 ic)

    const int gc0 = blockIdx.x * 64;
    const int gr0 = blockIdx.y * 4;
    const int b   = blockIdx.z;

    // row offsets (uniform) for input rows gr0-1 .. gr0+4
    unsigned rowoff[6]; bool rowok[6];
    #pragma unroll
    for (int j = 0; j < 6; ++j) {
        const int gr = gr0 - 1 + j;
        rowok[j]  = ((unsigned)gr < (unsigned)HH);
        const int grc = gr < 0 ? 0 : (gr > HH - 1 ? HH - 1 : gr);
        rowoff[j] = (unsigned)grc << 15;          // * WW * 128B
    }
    // per-lane col byte-offsets for kw = 0..2
    unsigned colb[3]; bool colok[3];
    #pragma unroll
    for (int kw = 0; kw < 3; ++kw) {
        const int gc = gc0 + wv * 16 + n_l + kw - 1;
        colok[kw] = ((unsigned)gc < (unsigned)WW);
        const int gcc = gc < 0 ? 0 : (gc > WW - 1 ? WW - 1 : gc);
        colb[kw] = ((unsigned)gcc << 7) + (G_l << 4);
    }

    const char* xTb = ws + AFRAG_BYTES + ((size_t)b << 23);   // b * 8 MB
    const unsigned abase = (n_l << 6) + (G_l << 4);

    floatx4 acc[4][4];
    #pragma unroll
    for (int og = 0; og < 4; ++og)
        #pragma unroll
        for (int fr = 0; fr < 4; ++fr) acc[og][fr] = (floatx4){0.f, 0.f, 0.f, 0.f};

    #pragma unroll
    for (int h = 0; h < 2; ++h) {
        #pragma unroll
        for (int tap = 0; tap < 9; ++tap) {
            const int kc = h * 9 + tap;
            const int kh = tap / 3, kw = tap % 3;
            const int hb = h * 64;
            // 4 B-frags (one per output row), masked for halo
            uint4 bv[4];
            #pragma unroll
            for (int fr = 0; fr < 4; ++fr) {
                const uint4 t = *reinterpret_cast<const uint4*>(
                    xTb + rowoff[fr + kh] + colb[kw] + hb);
                const unsigned m = (rowok[fr + kh] && colok[kw]) ? 0xFFFFFFFFu : 0u;
                bv[fr].x = t.x & m; bv[fr].y = t.y & m;
                bv[fr].z = t.z & m; bv[fr].w = t.w & m;
            }
            // 4 A-frags x 4 B-frags outer product
            #pragma unroll
            for (int og = 0; og < 4; ++og) {
                const short8 a = *reinterpret_cast<const short8*>(
                    ws + (kc << 12) + (og << 10) + abase);
                #pragma unroll
                for (int fr = 0; fr < 4; ++fr)
                    acc[og][fr] = __builtin_amdgcn_mfma_f32_16x16x32_bf16(
                        a, __builtin_bit_cast(short8, bv[fr]), acc[og][fr], 0, 0, 0);
            }
        }
    }

    // epilogue: oc = og*16 + G_l*4 + ri
    float* ob = out + ((size_t)b * OCH + (G_l << 2)) * HW
                    + (size_t)gr0 * WW + gc0 + (wv << 4) + n_l;
    #pragma unroll
    for (int og = 0; og < 4; ++og)
        #pragma unroll
        for (int fr = 0; fr < 4; ++fr)
            #pragma unroll
            for (int ri = 0; ri < 4; ++ri)
                ob[(size_t)(og * 16 + ri) * HW + fr * WW] = acc[og][fr][ri];
}

// ============ fallback: R4 validated LDS-staging conv (if ws too small) ============
#define TR 4
#define TC 64
#define XROWS 6
#define XCOLS 66
#define XPIXB 64
#define XROWB (XCOLS * XPIXB)
#define XHALFB (XROWS * XROWB)
#define LDS_BYTES (2 * XHALFB)

__global__ __launch_bounds__(256, 2) void conv_mfma_fallback(
    const float* __restrict__ x,
    const unsigned int* __restrict__ wfrag,
    float* __restrict__ out)
{
    __shared__ __align__(16) char lds[LDS_BYTES];
    const int tid  = threadIdx.x;
    const int lane = tid & 63;
    const int wv   = tid >> 6;
    const int n_l  = lane & 15;
    const int G_l  = lane >> 4;

    short8 afrag[18];
    {
        const int oc_l = (wv << 4) + n_l;
        const char* wsb = (const char*)wfrag;
        #pragma unroll
        for (int kc = 0; kc < 18; ++kc)
            afrag[kc] = *reinterpret_cast<const short8*>(
                wsb + (((kc * 64 + oc_l) * 4 + G_l) << 4));
    }

    const int gr0 = blockIdx.y * TR;
    const int gc0 = blockIdx.x * TC;
    const int b   = blockIdx.z;
    const float* xb = x + (size_t)b * ICH * HW;

    for (int p = wv; p < 48; p += 4) {
        const int h  = p / 24;
        const int pr = (p % 24) >> 2;
        const int G  = p & 3;
        const int gr = gr0 - 1 + pr;
        const int icb = h * 32 + G * 8;
        const bool rok = ((unsigned)gr < (unsigned)HH);
        {
            const float* src = xb + (size_t)icb * HW + (size_t)gr * WW + gc0 + lane;
            float v[8];
            #pragma unroll
            for (int qq = 0; qq < 8; ++qq) v[qq] = rok ? src[(size_t)qq * HW] : 0.f;
            const int pc = lane + 1;
            const int addr = h*XHALFB + pr*XROWB + pc*XPIXB + ((G ^ ((pc >> 1) & 3)) << 4);
            uint4 w4; w4.x = pk2(v[0], v[1]); w4.y = pk2(v[2], v[3]);
            w4.z = pk2(v[4], v[5]); w4.w = pk2(v[6], v[7]);
            *reinterpret_cast<uint4*>(&lds[addr]) = w4;
        }
        if (lane < 2) {
            const int pc = lane * 65;
            const int gc = gc0 - 1 + pc;
            const bool ok = rok && ((unsigned)gc < (unsigned)WW);
            const float* src = xb + (size_t)icb * HW + (size_t)gr * WW + gc;
            float v[8];
            #pragma unroll
            for (int qq = 0; qq < 8; ++qq) v[qq] = ok ? src[(size_t)qq * HW] : 0.f;
            const int addr = h*XHALFB + pr*XROWB + pc*XPIXB + ((G ^ ((pc >> 1) & 3)) << 4);
            uint4 w4; w4.x = pk2(v[0], v[1]); w4.y = pk2(v[2], v[3]);
            w4.z = pk2(v[4], v[5]); w4.w = pk2(v[6], v[7]);
            *reinterpret_cast<uint4*>(&lds[addr]) = w4;
        }
    }
    __syncthreads();

    int colp[4][3];
    #pragma unroll
    for (int cb = 0; cb < 4; ++cb)
        #pragma unroll
        for (int kw = 0; kw < 3; ++kw) {
            const int pcv = cb * 16 + n_l + kw;
            colp[cb][kw] = pcv * XPIXB + ((G_l ^ ((pcv >> 1) & 3)) << 4);
        }

    floatx4 acc[16];
    #pragma unroll
    for (int f = 0; f < 16; ++f) acc[f] = (floatx4){0.f, 0.f, 0.f, 0.f};

    #pragma unroll
    for (int kc = 0; kc < 18; ++kc) {
        const int h = kc / 9, tap = kc % 9;
        const int kh = tap / 3, kw = tap % 3;
        #pragma unroll
        for (int f = 0; f < 16; ++f) {
            const int fr = f >> 2, cb = f & 3;
            const short8 bfrag = *reinterpret_cast<const short8*>(
                &lds[h*XHALFB + (fr + kh)*XROWB + colp[cb][kw]]);
            acc[f] = __builtin_amdgcn_mfma_f32_16x16x32_bf16(afrag[kc], bfrag, acc[f], 0, 0, 0);
        }
    }

    float* ob = out + ((size_t)(b*OCH + (wv << 4) + (G_l << 2)) * HW)
                    + (size_t)gr0 * WW + gc0 + n_l;
    #pragma unroll
    for (int f = 0; f < 16; ++f) {
        const int fr = f >> 2, cb = f & 3;
        #pragma unroll
        for (int ri = 0; ri < 4; ++ri)
            ob[(size_t)ri * HW + fr * WW + cb * 16] = acc[f][ri];
    }
}

extern "C" void kernel_launch(void* const* d_in, const int* in_sizes, int n_in,
                              void* d_out, int out_size, void* d_ws, size_t ws_size,
                              hipStream_t stream) {
    const float* x = (const float*)d_in[0];
    const float* w = (const float*)d_in[1];
    float* out = (float*)d_out;
    unsigned int* wsf = (unsigned int*)d_ws;

    weight_prep_kernel<<<dim3(4), 64, 0, stream>>>(w, wsf);

    if (ws_size >= WS_NEEDED) {
        unsigned int* xT = (unsigned int*)((char*)d_ws + AFRAG_BYTES);
        transpose_kernel<<<dim3(4, HH, BATCH), 256, 0, stream>>>(x, xT);
        conv_mfma_global<<<dim3(4, 64, BATCH), 256, 0, stream>>>((const char*)d_ws, out);
    } else {
        conv_mfma_fallback<<<dim3(4, 64, BATCH), 256, 0, stream>>>(x, wsf, out);
    }
}